// Round 8
// baseline (641.561 us; speedup 1.0000x reference)
//
#include <hip/hip_runtime.h>
#include <hip/hip_bf16.h>

// Problem constants (GCN autoencoder)
#define N_NODES 10000
#define N_FEAT  512
#define HIDDEN  32
#define CODE    16

typedef __attribute__((ext_vector_type(8))) short  short8;
typedef __attribute__((ext_vector_type(4))) float  floatx4;

__device__ __forceinline__ float bf2f(unsigned short h) {
    return __uint_as_float(((unsigned int)h) << 16);
}
__device__ __forceinline__ unsigned short f2bf(float f) {
    unsigned int u = __float_as_uint(f);
    u += 0x7fffu + ((u >> 16) & 1u);   // RNE
    return (unsigned short)(u >> 16);
}
__device__ __forceinline__ float load_f(const void* p, size_t i, int isf32) {
    return isf32 ? ((const float*)p)[i] : bf2f(((const unsigned short*)p)[i]);
}
__device__ __forceinline__ int get_idx(const int* p, int e, int is64) {
    return is64 ? p[2 * (size_t)e] : p[e];   // LE low half holds value (<10000)
}

// ---------------------------------------------------------------------------
// K0: dtype detector (insurance; expectation: all fp32, int32 — flags 1,1,1,1,0,0).
// ---------------------------------------------------------------------------
__global__ __launch_bounds__(384) void k_detect(const unsigned short* __restrict__ t0,
                                                const unsigned short* __restrict__ t1,
                                                const unsigned short* __restrict__ t2,
                                                const unsigned short* __restrict__ t3,
                                                const int* __restrict__ i0,
                                                const int* __restrict__ i1,
                                                int* __restrict__ flags) {
    const int w    = threadIdx.x >> 6;
    const int lane = threadIdx.x & 63;
    unsigned int m = 0;
    if (w < 4) {
        const unsigned short* p = (w == 0) ? t0 : (w == 1) ? t1 : (w == 2) ? t2 : t3;
        for (int i = lane; i < 128; i += 64) {
            unsigned int v = (unsigned int)p[2 * i] & 0x7fffu;
            m = m > v ? m : v;
        }
    } else {
        const int* p = (w == 4) ? i0 : i1;
        for (int i = lane; i < 128; i += 64) {
            m |= (unsigned int)p[2 * i + 1];
        }
    }
#pragma unroll
    for (int off = 32; off > 0; off >>= 1) {
        unsigned int o = (unsigned int)__shfl_down((int)m, off, 64);
        m = (w < 4) ? (m > o ? m : o) : (m | o);
    }
    if (lane == 0) flags[w] = (w < 4) ? (m >= 0x5000u ? 1 : 0) : (m == 0u ? 1 : 0);
}

// ---------------------------------------------------------------------------
// K1: XW1 = x @ W1 (R3 fp32 fast path) + zeroes Hacc and Zacc (R6 fold).
// ---------------------------------------------------------------------------
__global__ __launch_bounds__(256) void k_xw1(const void* __restrict__ x,
                                             const void* __restrict__ W1,
                                             float* __restrict__ XW1,
                                             float* __restrict__ Hacc,
                                             float* __restrict__ Zacc,
                                             int zero_acc,
                                             const int* __restrict__ flags) {
    const int xf32  = flags[0];
    const int w1f32 = flags[1];
    int t = blockIdx.x * 256 + threadIdx.x;
    if (t >= N_NODES * HIDDEN) return;
    if (zero_acc) {
        Hacc[t] = 0.f;                         // 320000 = N_NODES*HIDDEN exact
        if (t < N_NODES * CODE) Zacc[t] = 0.f; // first 160000 threads
    }
    const int n = t >> 5;
    const int c = t & 31;

    if (xf32 && w1f32) {               // expected path, wave-uniform branch
        const float* xr = (const float*)x + (size_t)n * N_FEAT;
        const float* w1 = (const float*)W1;
        float acc = 0.f;
#pragma unroll 4
        for (int k = 0; k < N_FEAT; k += 4) {
            floatx4 xa = *(const floatx4*)(xr + k);
            acc += xa[0] * w1[(k + 0) * HIDDEN + c];
            acc += xa[1] * w1[(k + 1) * HIDDEN + c];
            acc += xa[2] * w1[(k + 2) * HIDDEN + c];
            acc += xa[3] * w1[(k + 3) * HIDDEN + c];
        }
        XW1[t] = acc;
        return;
    }

    float acc = 0.f;                   // generic fallback
#pragma unroll 8
    for (int k = 0; k < N_FEAT; ++k) {
        float a = load_f(x,  (size_t)n * N_FEAT + k, xf32);
        float b = load_f(W1, (size_t)k * HIDDEN + c, w1f32);
        acc += a * b;
    }
    XW1[t] = acc;
}

// ---------------------------------------------------------------------------
// K2: Hacc[dst] += ew * XW1[src]  (32 feats/edge, scalar fp32 atomics — R4/R6
// proven; gfx950 has no packed-fp32 atomic, R7 confirmed at compile time).
// ---------------------------------------------------------------------------
__global__ __launch_bounds__(256) void k_spmm32(const void* __restrict__ ew,
                                                const int* __restrict__ src,
                                                const int* __restrict__ dst,
                                                const float* __restrict__ Xin,
                                                float* __restrict__ Hacc, int E,
                                                const int* __restrict__ flags) {
    const int ewf32 = flags[3];
    const int s64   = flags[4];
    const int d64   = flags[5];
    int t = blockIdx.x * 256 + threadIdx.x;
    int e = t >> 5;
    int f = t & 31;
    if (e >= E) return;
    float w = load_f(ew, e, ewf32);
    int   s = get_idx(src, e, s64);
    int   d = get_idx(dst, e, d64);
    float v = Xin[(size_t)s * HIDDEN + f] * w;
    atomicAdd(&Hacc[(size_t)d * HIDDEN + f], v);
}

// ---------------------------------------------------------------------------
// K4 (R6 fused): Zacc[dst][f] += ew * (relu(Hacc[src]) · W2[:,f]).
// ---------------------------------------------------------------------------
__global__ __launch_bounds__(256) void k_spmm16f(const void* __restrict__ ew,
                                                 const int* __restrict__ src,
                                                 const int* __restrict__ dst,
                                                 const float* __restrict__ Hacc,
                                                 const void* __restrict__ W2,
                                                 float* __restrict__ Zacc, int E,
                                                 const int* __restrict__ flags) {
    const int w2f32 = flags[2];
    const int ewf32 = flags[3];
    const int s64   = flags[4];
    const int d64   = flags[5];
    int t = blockIdx.x * 256 + threadIdx.x;
    int e = t >> 4;
    int f = t & 15;
    if (e >= E) return;
    float w = load_f(ew, e, ewf32);
    int   s = get_idx(src, e, s64);
    int   d = get_idx(dst, e, d64);
    const float* hr = Hacc + (size_t)s * HIDDEN;
    float acc = 0.f;
#pragma unroll
    for (int k = 0; k < HIDDEN; ++k) {
        float h = hr[k];
        h = h > 0.f ? h : 0.f;
        acc += h * load_f(W2, k * CODE + f, w2f32);
    }
    atomicAdd(&Zacc[(size_t)d * CODE + f], w * acc);
}

// ---------------------------------------------------------------------------
// K6: out = sigmoid(Z @ Z^T), fp32 Z input; in-register f2bf (same RNE on A
// and B frags -> symmetry intact). R3 LDS-staged full-line drain retained.
// ---------------------------------------------------------------------------
#define TLD 68   // LDS row stride in floats (64 data + 4 pad; 272B = 17*16B)

__device__ __forceinline__ short8 cvt_frag(const float* __restrict__ Z, int row, int quad) {
    short8 r = {0, 0, 0, 0, 0, 0, 0, 0};
    if (quad < 2) {
        floatx4 a = *(const floatx4*)(Z + (size_t)row * CODE + quad * 8);
        floatx4 b = *(const floatx4*)(Z + (size_t)row * CODE + quad * 8 + 4);
        r[0] = (short)f2bf(a[0]); r[1] = (short)f2bf(a[1]);
        r[2] = (short)f2bf(a[2]); r[3] = (short)f2bf(a[3]);
        r[4] = (short)f2bf(b[0]); r[5] = (short)f2bf(b[1]);
        r[6] = (short)f2bf(b[2]); r[7] = (short)f2bf(b[3]);
    }
    return r;
}

__global__ __launch_bounds__(256) void k_dec(const float* __restrict__ Z,
                                             float* __restrict__ out) {
    __shared__ float tile[64 * TLD];   // 17.4 KB

    const int wave = threadIdx.x >> 6;
    const int lane = threadIdx.x & 63;
    const int l16  = lane & 15;
    const int quad = lane >> 4;

    const int rblk = blockIdx.y * 64;
    const int cblk = blockIdx.x * 64;
    const int r0   = rblk + wave * 16;

    int ra = r0 + l16;
    if (ra > N_NODES - 1) ra = N_NODES - 1;
    short8 afr = cvt_frag(Z, ra, quad);

#pragma unroll
    for (int t = 0; t < 4; ++t) {
        int cb = cblk + t * 16 + l16;
        if (cb > N_NODES - 1) cb = N_NODES - 1;
        short8 bfr = cvt_frag(Z, cb, quad);
        floatx4 z4 = {0.f, 0.f, 0.f, 0.f};
        floatx4 acc = __builtin_amdgcn_mfma_f32_16x16x32_bf16(afr, bfr, z4, 0, 0, 0);
        const int lrow = wave * 16 + quad * 4;
        const int lcol = t * 16 + l16;
#pragma unroll
        for (int r = 0; r < 4; ++r) {
            tile[(lrow + r) * TLD + lcol] = acc[r];
        }
    }
    __syncthreads();

    const int drow = threadIdx.x >> 4;          // 0..15
    const int dcol = (threadIdx.x & 15) * 4;    // 0,4,..,60
#pragma unroll
    for (int p = 0; p < 4; ++p) {
        const int lr = p * 16 + drow;
        floatx4 v;
#pragma unroll
        for (int j = 0; j < 4; ++j) {
            float s = tile[lr * TLD + dcol + j];
            float e = __builtin_amdgcn_exp2f(-1.442695041f * s);
            v[j] = __builtin_amdgcn_rcpf(1.f + e);
        }
        const int grow = rblk + lr;
        const int gcol = cblk + dcol;
        if (grow < N_NODES && gcol < N_NODES) {   // N%4==0: float4-exact guard
            __builtin_nontemporal_store(v, (floatx4*)(out + (size_t)grow * N_NODES + gcol));
        }
    }
}

// ---------------------------------------------------------------------------
// Workspace layouts:
//  A (ws >= 3.21 MB): XW1 [0,320000) | Hacc [320000,640000) |
//    Zacc [640000,800000) | flags @800000.
//  PROBE extension (ws >= 5.13 MB): Hacc2 [800008,1120008) |
//    Zacc2 [1120008,1280008) — R8 instrumentation: duplicate spmm dispatches
//    into scratch; total-time delta vs R6 (544.6 us) = true spmm-pair cost.
//  B (fallback, ws >= 2.56 MB): Zacc over dead XW1 + 2 memsets.
// ---------------------------------------------------------------------------
extern "C" void kernel_launch(void* const* d_in, const int* in_sizes, int n_in,
                              void* d_out, int out_size, void* d_ws, size_t ws_size,
                              hipStream_t stream) {
    const void* x  = d_in[0];
    const void* W1 = d_in[1];
    const void* W2 = d_in[2];
    const void* ew = d_in[3];
    const int* src = (const int*)d_in[4];
    const int* dst = (const int*)d_in[5];
    float* out = (float*)d_out;
    const int E = in_sizes[3];   // 330000 edges

    float* ws   = (float*)d_ws;
    float* XW1  = ws;
    float* Hacc = ws + 320000;

    const size_t need_a     = (size_t)800006 * 4;
    const size_t need_probe = (size_t)1280008 * 4;
    const int layout_a = (ws_size >= need_a);
    const int probe    = (ws_size >= need_probe);

    float* Zacc  = layout_a ? (ws + 640000) : (ws + 160000);
    int*   flags = (int*)d_ws + (layout_a ? 800000 : 640000);
    float* Hacc2 = ws + 800008;   // scratch (probe only)
    float* Zacc2 = ws + 1120008;  // scratch (probe only)

    k_detect<<<1, 384, 0, stream>>>((const unsigned short*)x,
                                    (const unsigned short*)W1,
                                    (const unsigned short*)W2,
                                    (const unsigned short*)ew,
                                    src, dst, flags);

    if (!layout_a) {
        (void)hipMemsetAsync(Hacc, 0, 320000 * sizeof(float), stream);
        (void)hipMemsetAsync(Zacc, 0, 160000 * sizeof(float), stream);
    }

    k_xw1<<<(N_NODES * HIDDEN + 255) / 256, 256, 0, stream>>>(
        x, W1, XW1, Hacc, Zacc, layout_a ? 1 : 0, flags);

    k_spmm32<<<(E * 32 + 255) / 256, 256, 0, stream>>>(ew, src, dst, XW1, Hacc, E, flags);
    if (probe) {   // duplicate into scratch: pure added time = spmm32 cost
        k_spmm32<<<(E * 32 + 255) / 256, 256, 0, stream>>>(ew, src, dst, XW1, Hacc2, E, flags);
    }

    k_spmm16f<<<(E * 16 + 255) / 256, 256, 0, stream>>>(ew, src, dst, Hacc, W2, Zacc, E, flags);
    if (probe) {   // duplicate into scratch: pure added time = spmm16f cost
        k_spmm16f<<<(E * 16 + 255) / 256, 256, 0, stream>>>(ew, src, dst, Hacc, W2, Zacc2, E, flags);
    }

    dim3 grid((N_NODES + 63) / 64, (N_NODES + 63) / 64);
    k_dec<<<grid, 256, 0, stream>>>(Zacc, out);
}